// Round 7
// baseline (211.652 us; speedup 1.0000x reference)
//
#include <hip/hip_runtime.h>
#include <hip/hip_bf16.h>
#include <stdint.h>

// Problem constants
#define NFEAT 4096   // IN_FEATURES == OUT_FEATURES
#define MROWS 1024   // batch
// K (top-k) = 41, ALPHA_LR = 0.01, NUM_DYKSTRA_ITER = 50

typedef __bf16 bf16x8 __attribute__((ext_vector_type(8)));
typedef float  f32x4  __attribute__((ext_vector_type(4)));

__device__ __forceinline__ unsigned short bf16_rne(float f) {
    unsigned int u = __float_as_uint(f);
    unsigned int r = (u + 0x7fffu + ((u >> 16) & 1u)) >> 16;
    return (unsigned short)r;
}

#define GLDS(src, dst) \
    __builtin_amdgcn_global_load_lds((__attribute__((address_space(1))) const void*)(src), \
                                     (__attribute__((address_space(3))) void*)(dst), 16, 0, 0)

// ------- Kernel 1: Dykstra soft top-k (block 0) + x->bf16 cvt (blocks 1..1024)
__global__ __launch_bounds__(256) void dykstra_cvt_kernel(const float* __restrict__ alpha,
                                                          float* __restrict__ g,
                                                          const float* __restrict__ x,
                                                          unsigned short* __restrict__ xb) {
    __shared__ float red[8];
    const int tid = threadIdx.x;
    if (blockIdx.x != 0) {
        // --- cvt slice: 4096 floats per block ---
        const int bid = blockIdx.x - 1;
        const size_t base = (size_t)bid * 4096 + (size_t)tid * 16;
        float4 a0 = *(const float4*)(x + base);
        float4 a1 = *(const float4*)(x + base + 4);
        float4 a2 = *(const float4*)(x + base + 8);
        float4 a3 = *(const float4*)(x + base + 12);
        uint4 s0, s1;
        s0.x = bf16_rne(a0.x) | ((unsigned)bf16_rne(a0.y) << 16);
        s0.y = bf16_rne(a0.z) | ((unsigned)bf16_rne(a0.w) << 16);
        s0.z = bf16_rne(a1.x) | ((unsigned)bf16_rne(a1.y) << 16);
        s0.w = bf16_rne(a1.z) | ((unsigned)bf16_rne(a1.w) << 16);
        s1.x = bf16_rne(a2.x) | ((unsigned)bf16_rne(a2.y) << 16);
        s1.y = bf16_rne(a2.z) | ((unsigned)bf16_rne(a2.w) << 16);
        s1.z = bf16_rne(a3.x) | ((unsigned)bf16_rne(a3.y) << 16);
        s1.w = bf16_rne(a3.z) | ((unsigned)bf16_rne(a3.w) << 16);
        *(uint4*)(xb + base)     = s0;
        *(uint4*)(xb + base + 8) = s1;
        return;
    }
    // --- block 0: Dykstra ---
    float y[16], p[16], q[16], yp[16];
    #pragma unroll
    for (int j = 0; j < 16; ++j) {
        y[j] = alpha[tid + 256 * j] / 0.01f;   // y0 = x / l
        p[j] = 0.0f;
        q[j] = 0.0f;
    }
    for (int it = 0; it < 50; ++it) {
        float s = 0.0f;
        #pragma unroll
        for (int j = 0; j < 16; ++j) { yp[j] = y[j] + p[j]; s += yp[j]; }
        #pragma unroll
        for (int off = 32; off > 0; off >>= 1) s += __shfl_down(s, off, 64);
        const int half = (it & 1) * 4;          // WAR-safe double buffer
        if ((tid & 63) == 0) red[half + (tid >> 6)] = s;
        __syncthreads();
        const float S = (red[half] + red[half + 1]) + (red[half + 2] + red[half + 3]);
        const float shift = (S - 41.0f) / 4096.0f;  // (sum - k) / n
        #pragma unroll
        for (int j = 0; j < 16; ++j) {
            float y_hp = yp[j] - shift;
            p[j] = yp[j] - y_hp;            // NOT folded to 'shift' (fp semantics)
            float yq = y_hp + q[j];
            float yb = fminf(fmaxf(yq, 0.0f), 1.0f);
            q[j] = yq - yb;
            y[j] = yb;
        }
    }
    #pragma unroll
    for (int j = 0; j < 16; ++j) g[tid + 256 * j] = y[j];
}

// ---------------- Kernel 2: materialize W in bf16 ----------------
// W[r,c] = g[(r-c)%n] * V[(r-c)%n, c]; 256(r) x 64(c) tile per block.
// LDS band stride 66: anti-diagonal reads <=2-way conflicted (free, m136).
__global__ __launch_bounds__(256) void build_w_kernel(const float* __restrict__ V,
                                                      const float* __restrict__ g,
                                                      unsigned short* __restrict__ Wb) {
    __shared__ unsigned short vb[319 * 66];   // ~42 KB bf16, already *g
    const int tid = threadIdx.x;
    const int c0 = blockIdx.x * 64;
    const int r0 = blockIdx.y * 256;
    const int i0 = (r0 - c0 - 63) & 4095;
    #pragma unroll
    for (int j = 0; j < 20; ++j) {
        int idx = tid + 256 * j;
        if (idx < 5104) {
            int t   = idx >> 4;
            int col = (idx & 15) << 2;
            int i   = (i0 + t) & 4095;
            float gv = g[i];
            float4 v = *(const float4*)(V + (size_t)i * NFEAT + c0 + col);
            uint2 pk;
            pk.x = bf16_rne(v.x * gv) | ((unsigned)bf16_rne(v.y * gv) << 16);
            pk.y = bf16_rne(v.z * gv) | ((unsigned)bf16_rne(v.w * gv) << 16);
            *(uint2*)(vb + t * 66 + col) = pk;
        }
    }
    __syncthreads();
    const int dcp = tid & 15;
    const int drb = tid >> 4;
    #pragma unroll
    for (int j = 0; j < 16; ++j) {
        int dr = drb + 16 * j;
        int c  = dcp * 4;
        int tb = dr - c + 63;       // in [3, 318]
        unsigned short w0 = vb[tb * 66 + c];
        unsigned short w1 = vb[(tb - 1) * 66 + c + 1];
        unsigned short w2 = vb[(tb - 2) * 66 + c + 2];
        unsigned short w3 = vb[(tb - 3) * 66 + c + 3];
        uint2 st;
        st.x = w0 | ((unsigned)w1 << 16);
        st.y = w2 | ((unsigned)w3 << 16);
        *(uint2*)(Wb + (size_t)(r0 + dr) * NFEAT + c0 + c) = st;
    }
}

// ---------------- Kernel 3: split-K GEMM, 256x256, BK=64, 4x16-MFMA phases --
// v8: BK=64 / NBUF=2 (same 128 KB LDS), 16 K-tiles per block. Per K-tile:
//   P0: ds_read af[0-3]ks0 + bf[0-3]ks0 (8); GLDS A(kt+1) x4; BAR; lgkm0; 16 MFMA
//   P1: ds_read bf[4-7]ks0 (4);              GLDS B(kt+1) x4; BAR; lgkm0; 16 MFMA
//   P2: ds_read af ks1 + bf[0-7] ks1 (12);                    BAR; lgkm0; 16 MFMA
//   P3: vmcnt(0) [loads aged >=2 phases ~1250-1900cyc -> lands free]; BAR; 16 MFMA
// vs v7: lgkm0 drains 64->48, vmcnt waits 32->16, ds_read bursts spread.
// Race proof (v7 framework):
//  WAR: all ds_reads of a buffer issue by P2, drained by P2's lgkm0 (precedes
//    BAR-P3; P3 issues no reads). Stage into that buffer issues in P0 of the
//    NEXT K-tile, after the wave passed BAR-P3 -- which requires every wave
//    to have executed its P2 lgkm0. Proven ordering: slow-wave drain ->
//    slow-wave BAR-P3 arrival -> fast-wave BAR-P3 release -> fast-wave stage.
//  RAW: P3(kt)'s vmcnt(0) retires tile kt+1's 8 GLDS (own wave, aged 2-3
//    phases); BAR-P3 publishes cross-wave; first reads of that buffer are in
//    P0(kt+1). Tail kt=15: no stage, no wait (outstanding 0).
// LDS layout per buf: [ks(8)][row(256)][8] x {A,B} = 32+32 KB; kg-outer
// addressing identical in structure to v7 -> measured 0 bank conflicts.
// Staging roles: wave w = kslot w, row-blocks 0..3 (4 GLDS per matrix).
// Grid (16,4,4) = 256 blocks = 1/CU; same-n0 blocks share an XCD.
__global__ __launch_bounds__(512, 2) void gemm_kernel(const unsigned short* __restrict__ A,
                                                      const unsigned short* __restrict__ B,
                                                      float* __restrict__ C0,
                                                      float* __restrict__ Cp) {
    __shared__ unsigned short As[2][16384];   // 32 KB per buf
    __shared__ unsigned short Bs[2][16384];
    const int tid  = threadIdx.x;
    const int lane = tid & 63;
    const int w    = tid >> 6;       // 0..7
    const int wm   = w & 3;          // m strip (64 rows)
    const int wn   = w >> 2;         // n strip (128 cols)
    const int m0   = blockIdx.y * 256;
    const int n0   = blockIdx.x * 256;
    const int kbase = blockIdx.z * 1024;   // 16 K-tiles x BK=64

    f32x4 acc[4][8];
    #pragma unroll
    for (int i = 0; i < 4; ++i)
        #pragma unroll
        for (int j = 0; j < 8; ++j)
            acc[i][j] = (f32x4){0.f, 0.f, 0.f, 0.f};

    // staging: wave w covers kslot ks=w; 4 row-blocks per matrix
    const unsigned short* aS = A + (size_t)(m0 + lane) * NFEAT + kbase + w * 8;
    const unsigned short* bS = B + (size_t)(n0 + lane) * NFEAT + kbase + w * 8;
    const int sD = w * 2048;   // LDS elem offset of kslot w (+ lane*8 by HW)

    auto stageA = [&](int kt) {
        const int ko = kt * 64;  const int nb = kt & 1;
        GLDS(aS + ko,               As[nb] + sD);
        GLDS(aS + ko +  64 * NFEAT, As[nb] + sD + 512);
        GLDS(aS + ko + 128 * NFEAT, As[nb] + sD + 1024);
        GLDS(aS + ko + 192 * NFEAT, As[nb] + sD + 1536);
    };
    auto stageB = [&](int kt) {
        const int ko = kt * 64;  const int nb = kt & 1;
        GLDS(bS + ko,               Bs[nb] + sD);
        GLDS(bS + ko +  64 * NFEAT, Bs[nb] + sD + 512);
        GLDS(bS + ko + 128 * NFEAT, Bs[nb] + sD + 1024);
        GLDS(bS + ko + 192 * NFEAT, Bs[nb] + sD + 1536);
    };

    const int kg4 = lane >> 4;
    const int lm  = lane & 15;
    const int aBase = kg4 * 2048 + (wm * 64 + lm) * 8;   // ks32=0; +8192 for ks32=1
    const int bBase = kg4 * 2048 + (wn * 128 + lm) * 8;

#define MMA8(A0, A1, A2, A3, B0, B1, NI0, NI1)                                              \
    acc[0][NI0] = __builtin_amdgcn_mfma_f32_16x16x32_bf16(A0, B0, acc[0][NI0], 0, 0, 0);    \
    acc[1][NI0] = __builtin_amdgcn_mfma_f32_16x16x32_bf16(A1, B0, acc[1][NI0], 0, 0, 0);    \
    acc[2][NI0] = __builtin_amdgcn_mfma_f32_16x16x32_bf16(A2, B0, acc[2][NI0], 0, 0, 0);    \
    acc[3][NI0] = __builtin_amdgcn_mfma_f32_16x16x32_bf16(A3, B0, acc[3][NI0], 0, 0, 0);    \
    acc[0][NI1] = __builtin_amdgcn_mfma_f32_16x16x32_bf16(A0, B1, acc[0][NI1], 0, 0, 0);    \
    acc[1][NI1] = __builtin_amdgcn_mfma_f32_16x16x32_bf16(A1, B1, acc[1][NI1], 0, 0, 0);    \
    acc[2][NI1] = __builtin_amdgcn_mfma_f32_16x16x32_bf16(A2, B1, acc[2][NI1], 0, 0, 0);    \
    acc[3][NI1] = __builtin_amdgcn_mfma_f32_16x16x32_bf16(A3, B1, acc[3][NI1], 0, 0, 0)

#define BARX()   __builtin_amdgcn_s_barrier()
#define LGKM0()  asm volatile("s_waitcnt lgkmcnt(0)" ::: "memory")
#define SB0()    __builtin_amdgcn_sched_barrier(0)
#define PRIO1()  __builtin_amdgcn_s_setprio(1)
#define PRIO0()  __builtin_amdgcn_s_setprio(0)

#define KS64(KT, STG, VME) do {                                                             \
    const int _cur = (KT) & 1;                                                              \
    const unsigned short* aRd = As[_cur] + aBase;                                           \
    const unsigned short* bRd = Bs[_cur] + bBase;                                           \
    bf16x8 a0, a1, a2, a3, b0, b1, b2, b3, b4, b5, b6, b7;                                  \
    /* ---- P0: af+bf[0-3] @ks0; stage A(kt+1) ---- */                                      \
    a0 = *(const bf16x8*)(aRd);        a1 = *(const bf16x8*)(aRd + 128);                    \
    a2 = *(const bf16x8*)(aRd + 256);  a3 = *(const bf16x8*)(aRd + 384);                    \
    b0 = *(const bf16x8*)(bRd);        b1 = *(const bf16x8*)(bRd + 128);                    \
    b2 = *(const bf16x8*)(bRd + 256);  b3 = *(const bf16x8*)(bRd + 384);                    \
    if (STG) stageA((KT) + 1);                                                              \
    BARX(); LGKM0(); SB0();                                                                 \
    PRIO1(); MMA8(a0, a1, a2, a3, b0, b1, 0, 1); MMA8(a0, a1, a2, a3, b2, b3, 2, 3);        \
    PRIO0();                                                                                \
    /* ---- P1: bf[4-7] @ks0; stage B(kt+1) ---- */                                         \
    b4 = *(const bf16x8*)(bRd + 512);  b5 = *(const bf16x8*)(bRd + 640);                    \
    b6 = *(const bf16x8*)(bRd + 768);  b7 = *(const bf16x8*)(bRd + 896);                    \
    if (STG) stageB((KT) + 1);                                                              \
    BARX(); LGKM0(); SB0();                                                                 \
    PRIO1(); MMA8(a0, a1, a2, a3, b4, b5, 4, 5); MMA8(a0, a1, a2, a3, b6, b7, 6, 7);        \
    PRIO0();                                                                                \
    /* ---- P2: af+bf[0-7] @ks1 (12 reads) ---- */                                          \
    a0 = *(const bf16x8*)(aRd + 8192);        a1 = *(const bf16x8*)(aRd + 8192 + 128);      \
    a2 = *(const bf16x8*)(aRd + 8192 + 256);  a3 = *(const bf16x8*)(aRd + 8192 + 384);      \
    b0 = *(const bf16x8*)(bRd + 8192);        b1 = *(const bf16x8*)(bRd + 8192 + 128);      \
    b2 = *(const bf16x8*)(bRd + 8192 + 256);  b3 = *(const bf16x8*)(bRd + 8192 + 384);      \
    b4 = *(const bf16x8*)(bRd + 8192 + 512);  b5 = *(const bf16x8*)(bRd + 8192 + 640);      \
    b6 = *(const bf16x8*)(bRd + 8192 + 768);  b7 = *(const bf16x8*)(bRd + 8192 + 896);      \
    BARX(); LGKM0(); SB0();                                                                 \
    PRIO1(); MMA8(a0, a1, a2, a3, b0, b1, 0, 1); MMA8(a0, a1, a2, a3, b2, b3, 2, 3);        \
    PRIO0();                                                                                \
    /* ---- P3: pure-reg MFMA; retire tile kt+1 (aged) ---- */                              \
    VME;                                                                                    \
    BARX(); SB0();                                                                          \
    PRIO1(); MMA8(a0, a1, a2, a3, b4, b5, 4, 5); MMA8(a0, a1, a2, a3, b6, b7, 6, 7);        \
    PRIO0();                                                                                \
} while (0)

    stageA(0); stageB(0);                      // prologue: 8 loads
    asm volatile("s_waitcnt vmcnt(0)" ::: "memory");
    BARX();
    #pragma unroll 1
    for (int kt = 0; kt < 15; ++kt) {
        KS64(kt, 1, asm volatile("s_waitcnt vmcnt(0)" ::: "memory"));
    }
    KS64(15, 0, (void)0);

    float* Cz = (blockIdx.z == 0) ? C0 : (Cp + (size_t)(blockIdx.z - 1) * MROWS * NFEAT);
    // C/D layout: col = lane&15, row = (lane>>4)*4 + reg  (m89-verified)
    const int crow = m0 + wm * 64 + (lane >> 4) * 4;
    const int ccol = n0 + wn * 128 + lm;
    #pragma unroll
    for (int mi = 0; mi < 4; ++mi)
        #pragma unroll
        for (int ni = 0; ni < 8; ++ni) {
            float* cp = Cz + (size_t)(crow + mi * 16) * NFEAT + ccol + ni * 16;
            #pragma unroll
            for (int r = 0; r < 4; ++r)
                cp[(size_t)r * NFEAT] = acc[mi][ni][r];
        }
}

// ---------------- Kernel 4: split-K reduce: out += sum of partials ----------
__global__ __launch_bounds__(256) void reduce_kernel(float* __restrict__ out,
                                                     const float* __restrict__ Cp) {
    const size_t i = (size_t)(blockIdx.x * 256 + threadIdx.x) * 4;
    float4 a = *(const float4*)(out + i);
    #pragma unroll
    for (int s = 0; s < 3; ++s) {
        float4 b = *(const float4*)(Cp + (size_t)s * MROWS * NFEAT + i);
        a.x += b.x; a.y += b.y; a.z += b.z; a.w += b.w;
    }
    *(float4*)(out + i) = a;
}

extern "C" void kernel_launch(void* const* d_in, const int* in_sizes, int n_in,
                              void* d_out, int out_size, void* d_ws, size_t ws_size,
                              hipStream_t stream) {
    const float* x     = (const float*)d_in[0];   // (1024, 4096) fp32
    const float* V     = (const float*)d_in[1];   // (4096, 4096) fp32
    const float* alpha = (const float*)d_in[2];   // (4096,) fp32
    float* out = (float*)d_out;                   // (1024, 4096) fp32

    char* ws = (char*)d_ws;
    const size_t xb_off = 16384;
    const size_t wb_off = xb_off + (size_t)MROWS * NFEAT * 2;   // + 8 MB
    const size_t cp_off = wb_off + (size_t)NFEAT * NFEAT * 2;   // +32 MB
    float* g           = (float*)ws;
    unsigned short* xb = (unsigned short*)(ws + xb_off);
    unsigned short* Wb = (unsigned short*)(ws + wb_off);
    float* Cp          = (float*)(ws + cp_off);                 // 48 MB (S=4)

    hipLaunchKernelGGL(dykstra_cvt_kernel, dim3(1025),   dim3(256), 0, stream, alpha, g, x, xb);
    hipLaunchKernelGGL(build_w_kernel,     dim3(64, 16), dim3(256), 0, stream, V, g, Wb);
    hipLaunchKernelGGL(gemm_kernel,        dim3(16, 4, 4), dim3(512), 0, stream, xb, Wb, out, Cp);
    hipLaunchKernelGGL(reduce_kernel,      dim3(MROWS * NFEAT / (256 * 4)), dim3(256), 0, stream,
                       out, Cp);
}